// Round 11
// baseline (160.887 us; speedup 1.0000x reference)
//
#include <hip/hip_runtime.h>
#include <math.h>

// B=4, T=48, W=8, H=8, C=32; d_ff=64; periods {2,3,4}. T%P==0 always.
// (1x1 + 3^4)/2 inception folded into one 81-tap conv (center tap 40).
// Padded in L,P,W,H -> branch-free 81 taps.
// R11: tail-free grid. Block = 4 waves = 4 t-cells, FULL output width per
// wave (16 MFMA/tap). Grid = 144 blocks (8 XCD x 18) -> exactly <=1 block/CU.
// Weights staged once per block (shared by 4 waves), 3-tap double-buffered
// chunks, issue-after-barrier pipeline (barrier's implicit vmcnt(0) drain is
// the wait; one-chunk prefetch window).

typedef __attribute__((ext_vector_type(8))) short bf16x8;
typedef __attribute__((ext_vector_type(4))) float f32x4;
typedef unsigned short u16;

#define XB0 0
#define XB1 1331200            // 4 * 26*4*3200
#define XB2 2483200            // XB1 + 4 * 18*5*3200
#define XTOT 3558400           // XB2 + 4 * 14*6*3200
#define W1OFF XTOT             // 165888 bf16: [tap 0..80][2048]
#define W2OFF (XTOT + 165888)  // 165888 bf16: [tap 0..80][2048]
#define H1OFF (XTOT + 331776)  // h1pad3 (C=64, swizzled cells)
#define HB0 0
#define HB1 2662400            // 4 * 26*4*6400
#define HB2 4966400            // HB1 + 4 * 18*5*6400
#define H1TOT 7116800
#define H2OFF_U16 (H1OFF + H1TOT)
#define H2_PER 393216          // fp32 per period: 192*64*32
#define PREP_N (XTOT + 331776)

__device__ __forceinline__ u16 f2bf(float f) {
    unsigned u = __float_as_uint(f);
    unsigned r = u + 0x7fffu + ((u >> 16) & 1u);
    return (u16)(r >> 16);
}
__device__ __forceinline__ float gelu_exact(float v) {
    return 0.5f * v * (1.0f + erff(v * 0.7071067811865476f));
}

// async copy of 1 KB: 64 lanes x 16 B. LDS dest = wave-uniform base + lane*16.
__device__ __forceinline__ void cp1k(const u16* g, u16* l, int lane) {
    __builtin_amdgcn_global_load_lds(
        (const __attribute__((address_space(1))) unsigned int*)(g + lane * 8),
        (__attribute__((address_space(3))) unsigned int*)(l + lane * 8),
        16, 0, 0);
}

// ---- prep (layouts unchanged from R9/R10) ----
template<int P>
__device__ __forceinline__ void prep_x(const float* __restrict__ x,
                                       u16* __restrict__ dst, int j) {
    constexpr int L = 48 / P;
    constexpr int SZ = (L + 2) * (P + 2) * 3200;
    int b = j / SZ; int r = j - b * SZ;
    int cell2d = r / 3200; int inner = r - cell2d * 3200;
    int cellpos = inner >> 5; int low = inner & 31;
    int sc = low >> 3, jj = low & 7;
    int c = ((sc ^ (cellpos & 3)) << 3) + jj;
    int wp = cellpos / 10, hp = cellpos - (cellpos / 10) * 10;
    int qp = cell2d % (P + 2), lp = cell2d / (P + 2);
    float v = 0.f;
    if (lp >= 1 && lp <= L && qp >= 1 && qp <= P &&
        wp >= 1 && wp <= 8 && hp >= 1 && hp <= 8) {
        int t = (lp - 1) * P + (qp - 1);
        v = x[((b * 48 + t) * 64 + (wp - 1) * 8 + (hp - 1)) * 32 + c];
    }
    dst[j] = f2bf(v);
}

__global__ __launch_bounds__(256) void prep(
    const float* __restrict__ x,
    const float* __restrict__ w1_0, const float* __restrict__ w1_1,
    const float* __restrict__ w2_0, const float* __restrict__ w2_1,
    u16* __restrict__ ws) {
    int i = blockIdx.x * 256 + threadIdx.x;
    if (i < XB1) {
        prep_x<2>(x, ws + XB0, i - XB0);
    } else if (i < XB2) {
        prep_x<3>(x, ws + XB1, i - XB1);
    } else if (i < XTOT) {
        prep_x<4>(x, ws + XB2, i - XB2);
    } else if (i < W2OFF) {
        // w1: [tap][chunk(256)*8+jj], chunk = (quad*4+nt4)*16+m
        int j = i - W1OFF;
        int tap = j >> 11; int r = j & 2047;
        int chunk = r >> 3, jj = r & 7;
        int m = chunk & 15, nt = (chunk >> 4) & 3, quad = chunk >> 6;
        int o = nt * 16 + m, c = quad * 8 + jj;
        float v = 0.5f * w1_1[(o * 32 + c) * 81 + tap];
        if (tap == 40) v += 0.5f * w1_0[o * 32 + c];
        ws[i] = f2bf(v);
    } else if (i < PREP_N) {
        // w2: [tap][chunk(256)*8+jj], chunk = ((ks*4+quad)*2+nt)*16+m
        int j = i - W2OFF;
        int tap = j >> 11; int r = j & 2047;
        int chunk = r >> 3, jj = r & 7;
        int m = chunk & 15, nt = (chunk >> 4) & 1;
        int quad = (chunk >> 5) & 3, ks = chunk >> 7;
        int o = nt * 16 + m, c = ks * 32 + quad * 8 + jj;
        float v = 0.5f * w2_1[(o * 64 + c) * 81 + tap];
        if (tap == 40) v += 0.5f * w2_0[o * 64 + c];
        ws[i] = f2bf(v);
    }
}

// ---- conv1 (C32->C64) + GELU. Block = 4 waves = 4 t-cells; wave: M=64
// positions of its t, N=64 (all o). Weights shared block-wide. ----
template<int P>
__device__ __forceinline__ void conv1_body(
    const u16* __restrict__ xpad, const u16* __restrict__ w1b,
    u16* __restrict__ h1pad, int tq, int bb,
    u16* __restrict__ s_w, u16* __restrict__ s_a) {
    constexpr int L = 48 / P;
    constexpr int XB = (P == 2) ? XB0 : (P == 3) ? XB1 : XB2;
    constexpr int HB = (P == 2) ? HB0 : (P == 3) ? HB1 : HB2;
    constexpr int XSTR = (L + 2) * (P + 2) * 3200;
    constexpr int HSTR = (L + 2) * (P + 2) * 6400;

    int tid = threadIdx.x;
    int lane = tid & 63, wv = tid >> 6;   // wv = tloc (its t-cell)
    int m = lane & 15, quad = lane >> 4;

    const u16* xcs[4];
#pragma unroll
    for (int c4 = 0; c4 < 4; ++c4) {
        int tt = tq * 4 + c4;
        int ll = tt / P, qq = tt - ll * P;
        xcs[c4] = xpad + XB + bb * XSTR + (ll * (P + 2) + qq) * 3200;
    }

    int sp[4];
#pragma unroll
    for (int mt = 0; mt < 4; ++mt) {
        int pos = mt * 16 + m;
        sp[mt] = (pos >> 3) * 10 + (pos & 7);
    }

    f32x4 acc[4][4];
#pragma unroll
    for (int mt = 0; mt < 4; ++mt)
#pragma unroll
        for (int nt = 0; nt < 4; ++nt) acc[mt][nt] = f32x4{0.f, 0.f, 0.f, 0.f};

    // weights chunk cgn = taps 3cgn..3cgn+2 (12 KB, 12 pieces / 4 waves)
    auto stageW = [&](int cgn) {
        const u16* src = w1b + (cgn * 3) * 2048;
        u16* dst = s_w + (cgn & 1) * 6144;
        int p0 = wv * 3;
#pragma unroll
        for (int i = 0; i < 3; ++i)
            cp1k(src + (p0 + i) * 512, dst + (p0 + i) * 512, lane);
    };
    // act group gg: 4 cells x 7 pieces = 28 pieces, split across 3 chunks
    auto stageA = [&](int gg, int k0, int k1) {
        int coff = ((gg / 3) * (P + 2) + (gg % 3)) * 3200;
        for (int k = k0 + wv; k < k1; k += 4) {
            int cell = k / 7, pc = k - (k / 7) * 7;
            cp1k(xcs[cell] + coff + pc * 512,
                 s_a + (cell * 2 + (gg & 1)) * 3584 + pc * 512, lane);
        }
    };

    stageW(0);
    stageA(0, 0, 28);

#pragma unroll 1
    for (int cg = 0; cg < 27; ++cg) {
        __syncthreads();   // implicit vmcnt(0): chunk cg delivered; all waves
                           // done with cg-1 -> safe to overwrite its buffers
        if (cg < 26) stageW(cg + 1);
        int grp = cg / 3, part = cg - grp * 3;
        if (grp < 8) stageA(grp + 1, part * 10, (part == 2) ? 28 : part * 10 + 10);

        const u16* bw = s_w + (cg & 1) * 6144;
        const u16* ba = s_a + (wv * 2 + (grp & 1)) * 3584;
        int dwb = part * 10;   // dw = part, dh = j
#pragma unroll
        for (int j = 0; j < 3; ++j) {
            const u16* tw = bw + j * 2048;
            bf16x8 wf[4];
#pragma unroll
            for (int nt = 0; nt < 4; ++nt)
                wf[nt] = *(const bf16x8*)(tw + (((quad * 4 + nt) * 16 + m) << 3));
            bf16x8 af[4];
#pragma unroll
            for (int mt = 0; mt < 4; ++mt) {
                int cellpos = sp[mt] + dwb + j;
                af[mt] = *(const bf16x8*)(ba + cellpos * 32 +
                                          ((quad ^ (cellpos & 3)) << 3));
            }
#pragma unroll
            for (int mt = 0; mt < 4; ++mt)
#pragma unroll
                for (int nt = 0; nt < 4; ++nt)
                    acc[mt][nt] = __builtin_amdgcn_mfma_f32_16x16x32_bf16(
                        af[mt], wf[nt], acc[mt][nt], 0, 0, 0);
        }
    }

    // epilogue: GELU -> bf16 -> swizzled h1pad cell (own t, all 64 o)
    int t = tq * 4 + wv;
    int l = t / P, q = t - l * P;
    u16* hcell = h1pad + HB + bb * HSTR + ((l + 1) * (P + 2) + (q + 1)) * 6400;
#pragma unroll
    for (int mt = 0; mt < 4; ++mt)
#pragma unroll
        for (int r = 0; r < 4; ++r) {
            int pos = mt * 16 + quad * 4 + r;
            int cellpos = ((pos >> 3) + 1) * 10 + (pos & 7) + 1;
#pragma unroll
            for (int nt = 0; nt < 4; ++nt) {
                int o = nt * 16 + m;
                hcell[cellpos * 64 + (((o >> 3) ^ (cellpos & 7)) << 3) + (o & 7)] =
                    f2bf(gelu_exact(acc[mt][nt][r]));
            }
        }
}

__global__ __launch_bounds__(256, 1) void conv1_k(
    const u16* __restrict__ ws_x, const u16* __restrict__ ws_w1,
    u16* __restrict__ ws_h1) {
    __shared__ __align__(16) u16 s_w[2 * 6144];   // 24 KB weight dbuf
    __shared__ __align__(16) u16 s_a[8 * 3584];   // 56 KB act [cell(4)][dbuf(2)]
    int g = blockIdx.x;
    int jid = (g & 7) * 18 + (g >> 3);            // XCD-chunked, 144 = 8*18
    int per = jid / 48; int rem = jid - per * 48;
    int bb = rem / 12; int tq = rem - bb * 12;
    if (per == 0)      conv1_body<2>(ws_x, ws_w1, ws_h1, tq, bb, s_w, s_a);
    else if (per == 1) conv1_body<3>(ws_x, ws_w1, ws_h1, tq, bb, s_w, s_a);
    else               conv1_body<4>(ws_x, ws_w1, ws_h1, tq, bb, s_w, s_a);
}

// ---- conv2 (C64->C32). Block = 4 waves = 4 t-cells; wave: M=64 positions
// of its t, N=32 (all o), K=64. ----
template<int P>
__device__ __forceinline__ void conv2_body(
    const u16* __restrict__ h1pad, const u16* __restrict__ w2b,
    float* __restrict__ h2per, int tq, int bb,
    u16* __restrict__ s_w, u16* __restrict__ s_a) {
    constexpr int L = 48 / P;
    constexpr int HB = (P == 2) ? HB0 : (P == 3) ? HB1 : HB2;
    constexpr int HSTR = (L + 2) * (P + 2) * 6400;

    int tid = threadIdx.x;
    int lane = tid & 63, wv = tid >> 6;
    int m = lane & 15, quad = lane >> 4;

    const u16* hcs[4];
#pragma unroll
    for (int c4 = 0; c4 < 4; ++c4) {
        int tt = tq * 4 + c4;
        int ll = tt / P, qq = tt - ll * P;
        hcs[c4] = h1pad + HB + bb * HSTR + (ll * (P + 2) + qq) * 6400;
    }

    int sp[4];
#pragma unroll
    for (int mt = 0; mt < 4; ++mt) {
        int pos = mt * 16 + m;
        sp[mt] = (pos >> 3) * 10 + (pos & 7);
    }

    f32x4 acc[4][2];
#pragma unroll
    for (int mt = 0; mt < 4; ++mt)
#pragma unroll
        for (int nt = 0; nt < 2; ++nt) acc[mt][nt] = f32x4{0.f, 0.f, 0.f, 0.f};

    auto stageW = [&](int cgn) {
        const u16* src = w2b + (cgn * 3) * 2048;
        u16* dst = s_w + (cgn & 1) * 6144;
        int p0 = wv * 3;
#pragma unroll
        for (int i = 0; i < 3; ++i)
            cp1k(src + (p0 + i) * 512, dst + (p0 + i) * 512, lane);
    };
    // act group gg: 4 cells x 13 pieces = 52 pieces, split across 3 chunks
    auto stageA = [&](int gg, int k0, int k1) {
        int coff = ((gg / 3) * (P + 2) + (gg % 3)) * 6400;
        for (int k = k0 + wv; k < k1; k += 4) {
            int cell = k / 13, pc = k - (k / 13) * 13;
            cp1k(hcs[cell] + coff + pc * 512,
                 s_a + (cell * 2 + (gg & 1)) * 6656 + pc * 512, lane);
        }
    };

    stageW(0);
    stageA(0, 0, 52);

#pragma unroll 1
    for (int cg = 0; cg < 27; ++cg) {
        __syncthreads();
        if (cg < 26) stageW(cg + 1);
        int grp = cg / 3, part = cg - grp * 3;
        if (grp < 8) stageA(grp + 1, part * 18, (part == 2) ? 52 : part * 18 + 18);

        const u16* bw = s_w + (cg & 1) * 6144;
        const u16* ba = s_a + (wv * 2 + (grp & 1)) * 6656;
        int dwb = part * 10;
#pragma unroll
        for (int j = 0; j < 3; ++j) {
            const u16* tw = bw + j * 2048;
            bf16x8 wf[2][2];   // [nt][ks]
#pragma unroll
            for (int nt = 0; nt < 2; ++nt)
#pragma unroll
                for (int ks = 0; ks < 2; ++ks)
                    wf[nt][ks] = *(const bf16x8*)(tw +
                        ((((ks * 4 + quad) * 2 + nt) * 16 + m) << 3));
            bf16x8 af[4][2];   // [mt][ks]
#pragma unroll
            for (int mt = 0; mt < 4; ++mt) {
                int cellpos = sp[mt] + dwb + j;
#pragma unroll
                for (int ks = 0; ks < 2; ++ks)
                    af[mt][ks] = *(const bf16x8*)(ba + cellpos * 64 +
                        (((ks * 4 + quad) ^ (cellpos & 7)) << 3));
            }
#pragma unroll
            for (int mt = 0; mt < 4; ++mt)
#pragma unroll
                for (int ks = 0; ks < 2; ++ks)
#pragma unroll
                    for (int nt = 0; nt < 2; ++nt)
                        acc[mt][nt] = __builtin_amdgcn_mfma_f32_16x16x32_bf16(
                            af[mt][ks], wf[nt][ks], acc[mt][nt], 0, 0, 0);
        }
    }

    int t = tq * 4 + wv;
    float* orow = h2per + (bb * 48 + t) * 2048;
#pragma unroll
    for (int mt = 0; mt < 4; ++mt)
#pragma unroll
        for (int nt = 0; nt < 2; ++nt)
#pragma unroll
            for (int r = 0; r < 4; ++r) {
                int pos = mt * 16 + quad * 4 + r;
                orow[pos * 32 + nt * 16 + m] = acc[mt][nt][r];
            }
}

__global__ __launch_bounds__(256, 1) void conv2_k(
    const u16* __restrict__ ws_h1, const u16* __restrict__ ws_w2,
    float* __restrict__ h2) {
    __shared__ __align__(16) u16 s_w[2 * 6144];   // 24 KB
    __shared__ __align__(16) u16 s_a[8 * 6656];   // 104 KB -> 128 KB total
    int g = blockIdx.x;
    int jid = (g & 7) * 18 + (g >> 3);            // same XCD mapping as conv1
    int per = jid / 48; int rem = jid - per * 48;
    int bb = rem / 12; int tq = rem - bb * 12;
    float* h2per = h2 + per * H2_PER;
    if (per == 0)      conv2_body<2>(ws_h1, ws_w2, h2per, tq, bb, s_w, s_a);
    else if (per == 1) conv2_body<3>(ws_h1, ws_w2, h2per, tq, bb, s_w, s_a);
    else               conv2_body<4>(ws_h1, ws_w2, h2per, tq, bb, s_w, s_a);
}

// ---- out = x + (h2_p0 + h2_p1 + h2_p2) / 3 ----
__global__ __launch_bounds__(256) void final_add(
    const float* __restrict__ x, const float* __restrict__ h2,
    float* __restrict__ out) {
    int i = blockIdx.x * 256 + threadIdx.x;
    float4 xv = ((const float4*)x)[i];
    float4 a = ((const float4*)h2)[i];
    float4 bv = ((const float4*)(h2 + H2_PER))[i];
    float4 cv = ((const float4*)(h2 + 2 * H2_PER))[i];
    const float s = 1.0f / 3.0f;
    float4 o;
    o.x = xv.x + (a.x + bv.x + cv.x) * s;
    o.y = xv.y + (a.y + bv.y + cv.y) * s;
    o.z = xv.z + (a.z + bv.z + cv.z) * s;
    o.w = xv.w + (a.w + bv.w + cv.w) * s;
    ((float4*)out)[i] = o;
}

extern "C" void kernel_launch(void* const* d_in, const int* in_sizes, int n_in,
                              void* d_out, int out_size, void* d_ws, size_t ws_size,
                              hipStream_t stream) {
    const float* x    = (const float*)d_in[0];
    const float* w1_0 = (const float*)d_in[1];
    const float* w1_1 = (const float*)d_in[2];
    const float* w2_0 = (const float*)d_in[3];
    const float* w2_1 = (const float*)d_in[4];
    float* out = (float*)d_out;

    u16* ws = (u16*)d_ws;
    u16* ws_x  = ws;
    u16* ws_w1 = ws + W1OFF;
    u16* ws_w2 = ws + W2OFF;
    u16* ws_h1 = ws + H1OFF;
    float* h2  = (float*)(ws + H2OFF_U16);

    (void)hipMemsetAsync(ws_h1, 0, (size_t)H1TOT * 2, stream);
    prep<<<PREP_N / 256, 256, 0, stream>>>(x, w1_0, w1_1, w2_0, w2_1, ws);
    conv1_k<<<144, 256, 0, stream>>>(ws_x, ws_w1, ws_h1);
    conv2_k<<<144, 256, 0, stream>>>(ws_h1, ws_w2, h2);
    final_add<<<H2_PER / 4 / 256, 256, 0, stream>>>(x, h2, out);
}

// Round 12
// 151.190 us; speedup vs baseline: 1.0641x; 1.0641x over previous
//
#include <hip/hip_runtime.h>
#include <math.h>

// B=4, T=48, W=8, H=8, C=32; d_ff=64; periods {2,3,4}. T%P==0 always.
// (1x1 + 3^4)/2 inception folded into one 81-tap conv (center tap 40).
// Padded in L,P,W,H -> branch-free 81 taps.
// R12 = R10 + non-draining pipeline: raw s_barrier + per-wave in-order
// s_waitcnt vmcnt(N) (prefetch of chunk cg+1 stays in flight across the
// barrier). 3-deep weight ring (race-safe vs lagging readers of cg-1),
// act dbuf by group (safe: last g-1 reader exits 2 barriers before g+1
// issues). Uniform per-wave DMA piece counts via benign duplicate pieces.

typedef __attribute__((ext_vector_type(8))) short bf16x8;
typedef __attribute__((ext_vector_type(4))) float f32x4;
typedef unsigned short u16;

#define XB0 0
#define XB1 1331200            // 4 * 26*4*3200
#define XB2 2483200            // XB1 + 4 * 18*5*3200
#define XTOT 3558400           // XB2 + 4 * 14*6*3200
#define W1OFF XTOT             // 165888 bf16: [tap 0..80][2048]
#define W2OFF (XTOT + 165888)  // 165888 bf16: [tap 0..80][2048]
#define H1OFF (XTOT + 331776)  // h1pad3 (C=64, swizzled cells)
#define HB0 0
#define HB1 2662400            // 4 * 26*4*6400
#define HB2 4966400            // HB1 + 4 * 18*5*6400
#define H1TOT 7116800
#define H2OFF_U16 (H1OFF + H1TOT)
#define H2_PER 393216          // fp32 per period: 192*64*32
#define PREP_N (XTOT + 331776)

#define WAITVM(N) asm volatile("s_waitcnt vmcnt(" #N ")" ::: "memory")
#define SBAR()    asm volatile("s_barrier" ::: "memory")

__device__ __forceinline__ u16 f2bf(float f) {
    unsigned u = __float_as_uint(f);
    unsigned r = u + 0x7fffu + ((u >> 16) & 1u);
    return (u16)(r >> 16);
}
__device__ __forceinline__ float gelu_exact(float v) {
    return 0.5f * v * (1.0f + erff(v * 0.7071067811865476f));
}

// async copy of 1 KB: 64 lanes x 16 B. LDS dest = wave-uniform base + lane*16.
__device__ __forceinline__ void cp1k(const u16* g, u16* l, int lane) {
    __builtin_amdgcn_global_load_lds(
        (const __attribute__((address_space(1))) unsigned int*)(g + lane * 8),
        (__attribute__((address_space(3))) unsigned int*)(l + lane * 8),
        16, 0, 0);
}

// ---- prep (layouts unchanged from R9/R10) ----
template<int P>
__device__ __forceinline__ void prep_x(const float* __restrict__ x,
                                       u16* __restrict__ dst, int j) {
    constexpr int L = 48 / P;
    constexpr int SZ = (L + 2) * (P + 2) * 3200;
    int b = j / SZ; int r = j - b * SZ;
    int cell2d = r / 3200; int inner = r - cell2d * 3200;
    int cellpos = inner >> 5; int low = inner & 31;
    int sc = low >> 3, jj = low & 7;
    int c = ((sc ^ (cellpos & 3)) << 3) + jj;
    int wp = cellpos / 10, hp = cellpos - (cellpos / 10) * 10;
    int qp = cell2d % (P + 2), lp = cell2d / (P + 2);
    float v = 0.f;
    if (lp >= 1 && lp <= L && qp >= 1 && qp <= P &&
        wp >= 1 && wp <= 8 && hp >= 1 && hp <= 8) {
        int t = (lp - 1) * P + (qp - 1);
        v = x[((b * 48 + t) * 64 + (wp - 1) * 8 + (hp - 1)) * 32 + c];
    }
    dst[j] = f2bf(v);
}

__global__ __launch_bounds__(256) void prep(
    const float* __restrict__ x,
    const float* __restrict__ w1_0, const float* __restrict__ w1_1,
    const float* __restrict__ w2_0, const float* __restrict__ w2_1,
    u16* __restrict__ ws) {
    int i = blockIdx.x * 256 + threadIdx.x;
    if (i < XB1) {
        prep_x<2>(x, ws + XB0, i - XB0);
    } else if (i < XB2) {
        prep_x<3>(x, ws + XB1, i - XB1);
    } else if (i < XTOT) {
        prep_x<4>(x, ws + XB2, i - XB2);
    } else if (i < W2OFF) {
        // w1: [tap][chunk(256)*8+jj], chunk = (quad*4+nt4)*16+m
        int j = i - W1OFF;
        int tap = j >> 11; int r = j & 2047;
        int chunk = r >> 3, jj = r & 7;
        int m = chunk & 15, nt = (chunk >> 4) & 3, quad = chunk >> 6;
        int o = nt * 16 + m, c = quad * 8 + jj;
        float v = 0.5f * w1_1[(o * 32 + c) * 81 + tap];
        if (tap == 40) v += 0.5f * w1_0[o * 32 + c];
        ws[i] = f2bf(v);
    } else if (i < PREP_N) {
        // w2: [tap][chunk(256)*8+jj], chunk = ((ks*4+quad)*2+nt)*16+m
        int j = i - W2OFF;
        int tap = j >> 11; int r = j & 2047;
        int chunk = r >> 3, jj = r & 7;
        int m = chunk & 15, nt = (chunk >> 4) & 1;
        int quad = (chunk >> 5) & 3, ks = chunk >> 7;
        int o = nt * 16 + m, c = ks * 32 + quad * 8 + jj;
        float v = 0.5f * w2_1[(o * 64 + c) * 81 + tap];
        if (tap == 40) v += 0.5f * w2_0[o * 64 + c];
        ws[i] = f2bf(v);
    }
}

// ---- conv1 (C32->C64) + GELU. Block = 4 waves: (tloc, nh) = (wv>>1, wv&1).
// Wave: M=64 (its t), N=32 (its o-half). Weights shared block-wide. ----
template<int P>
__device__ __forceinline__ void conv1_body(
    const u16* __restrict__ xpad, const u16* __restrict__ w1b,
    u16* __restrict__ h1pad, int tp, int bb,
    u16* __restrict__ s_w, u16* __restrict__ s_a) {
    constexpr int L = 48 / P;
    constexpr int XB = (P == 2) ? XB0 : (P == 3) ? XB1 : XB2;
    constexpr int HB = (P == 2) ? HB0 : (P == 3) ? HB1 : HB2;
    constexpr int XSTR = (L + 2) * (P + 2) * 3200;
    constexpr int HSTR = (L + 2) * (P + 2) * 6400;

    int tid = threadIdx.x;
    int lane = tid & 63, wv = tid >> 6;
    int m = lane & 15, quad = lane >> 4;
    int tloc = wv >> 1, nh = wv & 1;

    const u16* xcs[2];
#pragma unroll
    for (int c2 = 0; c2 < 2; ++c2) {
        int tt = tp * 2 + c2;
        int ll = tt / P, qq = tt - ll * P;
        xcs[c2] = xpad + XB + bb * XSTR + (ll * (P + 2) + qq) * 3200;
    }

    int sp[4];
#pragma unroll
    for (int mt = 0; mt < 4; ++mt) {
        int pos = mt * 16 + m;
        sp[mt] = (pos >> 3) * 10 + (pos & 7);
    }

    f32x4 acc[4][2];
#pragma unroll
    for (int mt = 0; mt < 4; ++mt)
#pragma unroll
        for (int nt = 0; nt < 2; ++nt) acc[mt][nt] = f32x4{0.f, 0.f, 0.f, 0.f};

    // weights chunk cgn = taps 3cgn..3cgn+2 (12 KB): 12 pieces, 3/wave.
    auto stageW = [&](int cgn) {
        const u16* src = w1b + (cgn * 3) * 2048;
        u16* dst = s_w + (cgn % 3) * 6144;
        int p0 = wv * 3;
#pragma unroll
        for (int i = 0; i < 3; ++i)
            cp1k(src + (p0 + i) * 512, dst + (p0 + i) * 512, lane);
    };
    // act group gg: 2 cells x 7 pieces = 14, padded to 16 -> 4/wave
    // (k>=14 duplicates piece 13: same src+dst, benign).
    auto stageA = [&](int gg) {
        int coff = ((gg / 3) * (P + 2) + (gg % 3)) * 3200;
#pragma unroll
        for (int i = 0; i < 4; ++i) {
            int k = wv * 4 + i; if (k >= 14) k = 13;
            int cell = k / 7, pc = k - (k / 7) * 7;
            cp1k(xcs[cell] + coff + pc * 512,
                 s_a + (cell * 2 + (gg & 1)) * 3584 + pc * 512, lane);
        }
    };

    // prologue: per wave 3 w-pieces + 4 a-pieces = 7 outstanding
    stageW(0);
    stageA(0);

#pragma unroll 1
    for (int cg = 0; cg < 27; ++cg) {
        // issue prefetch for cg+1, then wait for cg's pieces only
        // (in-order queue: leave exactly the new pieces outstanding).
        if (cg < 26) {
            stageW(cg + 1);
            if ((cg + 1) % 3 == 0) {           // cg = 2,5,...,23
                stageA((cg + 1) / 3);
                WAITVM(7);                     // 3 w + 4 a outstanding
            } else {
                WAITVM(3);                     // 3 w outstanding
            }
        } else {
            WAITVM(0);
        }
        SBAR();   // all waves' cg pieces delivered; no drain of cg+1

        int grp = cg / 3, part = cg - grp * 3;
        const u16* bw = s_w + (cg % 3) * 6144;
        const u16* ba = s_a + (tloc * 2 + (grp & 1)) * 3584;
        int dwb = part * 10;   // dw = part, dh = j
#pragma unroll
        for (int j = 0; j < 3; ++j) {
            const u16* tw = bw + j * 2048;
            bf16x8 wf[2];
#pragma unroll
            for (int nt = 0; nt < 2; ++nt)
                wf[nt] = *(const bf16x8*)(tw +
                    (((quad * 4 + nh * 2 + nt) * 16 + m) << 3));
            bf16x8 af[4];
#pragma unroll
            for (int mt = 0; mt < 4; ++mt) {
                int cellpos = sp[mt] + dwb + j;
                af[mt] = *(const bf16x8*)(ba + cellpos * 32 +
                                          ((quad ^ (cellpos & 3)) << 3));
            }
#pragma unroll
            for (int mt = 0; mt < 4; ++mt)
#pragma unroll
                for (int nt = 0; nt < 2; ++nt)
                    acc[mt][nt] = __builtin_amdgcn_mfma_f32_16x16x32_bf16(
                        af[mt], wf[nt], acc[mt][nt], 0, 0, 0);
        }
    }

    // epilogue: GELU -> bf16 -> swizzled h1pad cell (own t, own o-half)
    int t = tp * 2 + tloc;
    int l = t / P, q = t - l * P;
    u16* hcell = h1pad + HB + bb * HSTR + ((l + 1) * (P + 2) + (q + 1)) * 6400;
#pragma unroll
    for (int mt = 0; mt < 4; ++mt)
#pragma unroll
        for (int r = 0; r < 4; ++r) {
            int pos = mt * 16 + quad * 4 + r;
            int cellpos = ((pos >> 3) + 1) * 10 + (pos & 7) + 1;
#pragma unroll
            for (int nt = 0; nt < 2; ++nt) {
                int o = nh * 32 + nt * 16 + m;
                hcell[cellpos * 64 + (((o >> 3) ^ (cellpos & 7)) << 3) + (o & 7)] =
                    f2bf(gelu_exact(acc[mt][nt][r]));
            }
        }
}

__global__ __launch_bounds__(256) void conv1_k(
    const u16* __restrict__ ws_x, const u16* __restrict__ ws_w1,
    u16* __restrict__ ws_h1) {
    __shared__ __align__(16) u16 s_w[3 * 6144];   // 36 KB weight ring (3-deep)
    __shared__ __align__(16) u16 s_a[4 * 3584];   // 28 KB act [cell(2)][dbuf(2)]
    int g = blockIdx.x;
    int jid = (g & 7) * 36 + (g >> 3);            // XCD-chunked, 288 = 8*36
    int per = jid / 96; int rem = jid - per * 96;
    int bb = rem / 24; int tp = rem - bb * 24;
    if (per == 0)      conv1_body<2>(ws_x, ws_w1, ws_h1, tp, bb, s_w, s_a);
    else if (per == 1) conv1_body<3>(ws_x, ws_w1, ws_h1, tp, bb, s_w, s_a);
    else               conv1_body<4>(ws_x, ws_w1, ws_h1, tp, bb, s_w, s_a);
}

// ---- conv2 (C64->C32). Block = 4 waves: (tloc, mh) = (wv>>1, wv&1).
// Wave: M=32 (its pos-half), N=32 (all o), K=64. ----
template<int P>
__device__ __forceinline__ void conv2_body(
    const u16* __restrict__ h1pad, const u16* __restrict__ w2b,
    float* __restrict__ h2per, int tp, int bb,
    u16* __restrict__ s_w, u16* __restrict__ s_a) {
    constexpr int L = 48 / P;
    constexpr int HB = (P == 2) ? HB0 : (P == 3) ? HB1 : HB2;
    constexpr int HSTR = (L + 2) * (P + 2) * 6400;

    int tid = threadIdx.x;
    int lane = tid & 63, wv = tid >> 6;
    int m = lane & 15, quad = lane >> 4;
    int tloc = wv >> 1, mh = wv & 1;

    const u16* hcs[2];
#pragma unroll
    for (int c2 = 0; c2 < 2; ++c2) {
        int tt = tp * 2 + c2;
        int ll = tt / P, qq = tt - ll * P;
        hcs[c2] = h1pad + HB + bb * HSTR + (ll * (P + 2) + qq) * 6400;
    }

    int sp[2];
#pragma unroll
    for (int mt = 0; mt < 2; ++mt) {
        int pos = mh * 32 + mt * 16 + m;
        sp[mt] = (pos >> 3) * 10 + (pos & 7);
    }

    f32x4 acc[2][2];
#pragma unroll
    for (int mt = 0; mt < 2; ++mt)
#pragma unroll
        for (int nt = 0; nt < 2; ++nt) acc[mt][nt] = f32x4{0.f, 0.f, 0.f, 0.f};

    auto stageW = [&](int cgn) {
        const u16* src = w2b + (cgn * 3) * 2048;
        u16* dst = s_w + (cgn % 3) * 6144;
        int p0 = wv * 3;
#pragma unroll
        for (int i = 0; i < 3; ++i)
            cp1k(src + (p0 + i) * 512, dst + (p0 + i) * 512, lane);
    };
    // act group gg: 2 cells x 13 pieces = 26, padded to 28 -> 7/wave
    auto stageA = [&](int gg) {
        int coff = ((gg / 3) * (P + 2) + (gg % 3)) * 6400;
#pragma unroll
        for (int i = 0; i < 7; ++i) {
            int k = wv * 7 + i; if (k >= 26) k = 25;
            int cell = k / 13, pc = k - (k / 13) * 13;
            cp1k(hcs[cell] + coff + pc * 512,
                 s_a + (cell * 2 + (gg & 1)) * 6656 + pc * 512, lane);
        }
    };

    // prologue: 3 w + 7 a = 10 outstanding per wave
    stageW(0);
    stageA(0);

#pragma unroll 1
    for (int cg = 0; cg < 27; ++cg) {
        if (cg < 26) {
            stageW(cg + 1);
            if ((cg + 1) % 3 == 0) {
                stageA((cg + 1) / 3);
                WAITVM(10);                    // 3 w + 7 a outstanding
            } else {
                WAITVM(3);
            }
        } else {
            WAITVM(0);
        }
        SBAR();

        int grp = cg / 3, part = cg - grp * 3;
        const u16* bw = s_w + (cg % 3) * 6144;
        const u16* ba = s_a + (tloc * 2 + (grp & 1)) * 6656;
        int dwb = part * 10;
#pragma unroll
        for (int j = 0; j < 3; ++j) {
            const u16* tw = bw + j * 2048;
            bf16x8 wf[2][2];   // [nt][ks]
#pragma unroll
            for (int nt = 0; nt < 2; ++nt)
#pragma unroll
                for (int ks = 0; ks < 2; ++ks)
                    wf[nt][ks] = *(const bf16x8*)(tw +
                        ((((ks * 4 + quad) * 2 + nt) * 16 + m) << 3));
            bf16x8 af[2][2];   // [mt][ks]
#pragma unroll
            for (int mt = 0; mt < 2; ++mt) {
                int cellpos = sp[mt] + dwb + j;
#pragma unroll
                for (int ks = 0; ks < 2; ++ks)
                    af[mt][ks] = *(const bf16x8*)(ba + cellpos * 64 +
                        (((ks * 4 + quad) ^ (cellpos & 7)) << 3));
            }
#pragma unroll
            for (int mt = 0; mt < 2; ++mt)
#pragma unroll
                for (int ks = 0; ks < 2; ++ks)
#pragma unroll
                    for (int nt = 0; nt < 2; ++nt)
                        acc[mt][nt] = __builtin_amdgcn_mfma_f32_16x16x32_bf16(
                            af[mt][ks], wf[nt][ks], acc[mt][nt], 0, 0, 0);
        }
    }

    int t = tp * 2 + tloc;
    float* orow = h2per + (bb * 48 + t) * 2048;
#pragma unroll
    for (int mt = 0; mt < 2; ++mt)
#pragma unroll
        for (int nt = 0; nt < 2; ++nt)
#pragma unroll
            for (int r = 0; r < 4; ++r) {
                int pos = mh * 32 + mt * 16 + quad * 4 + r;
                orow[pos * 32 + nt * 16 + m] = acc[mt][nt][r];
            }
}

__global__ __launch_bounds__(256) void conv2_k(
    const u16* __restrict__ ws_h1, const u16* __restrict__ ws_w2,
    float* __restrict__ h2) {
    __shared__ __align__(16) u16 s_w[3 * 6144];   // 36 KB (3-deep)
    __shared__ __align__(16) u16 s_a[4 * 6656];   // 52 KB -> 88 KB total
    int g = blockIdx.x;
    int jid = (g & 7) * 36 + (g >> 3);            // same XCD mapping as conv1
    int per = jid / 96; int rem = jid - per * 96;
    int bb = rem / 24; int tp = rem - bb * 24;
    float* h2per = h2 + per * H2_PER;
    if (per == 0)      conv2_body<2>(ws_h1, ws_w2, h2per, tp, bb, s_w, s_a);
    else if (per == 1) conv2_body<3>(ws_h1, ws_w2, h2per, tp, bb, s_w, s_a);
    else               conv2_body<4>(ws_h1, ws_w2, h2per, tp, bb, s_w, s_a);
}

// ---- out = x + (h2_p0 + h2_p1 + h2_p2) / 3 ----
__global__ __launch_bounds__(256) void final_add(
    const float* __restrict__ x, const float* __restrict__ h2,
    float* __restrict__ out) {
    int i = blockIdx.x * 256 + threadIdx.x;
    float4 xv = ((const float4*)x)[i];
    float4 a = ((const float4*)h2)[i];
    float4 bv = ((const float4*)(h2 + H2_PER))[i];
    float4 cv = ((const float4*)(h2 + 2 * H2_PER))[i];
    const float s = 1.0f / 3.0f;
    float4 o;
    o.x = xv.x + (a.x + bv.x + cv.x) * s;
    o.y = xv.y + (a.y + bv.y + cv.y) * s;
    o.z = xv.z + (a.z + bv.z + cv.z) * s;
    o.w = xv.w + (a.w + bv.w + cv.w) * s;
    ((float4*)out)[i] = o;
}

extern "C" void kernel_launch(void* const* d_in, const int* in_sizes, int n_in,
                              void* d_out, int out_size, void* d_ws, size_t ws_size,
                              hipStream_t stream) {
    const float* x    = (const float*)d_in[0];
    const float* w1_0 = (const float*)d_in[1];
    const float* w1_1 = (const float*)d_in[2];
    const float* w2_0 = (const float*)d_in[3];
    const float* w2_1 = (const float*)d_in[4];
    float* out = (float*)d_out;

    u16* ws = (u16*)d_ws;
    u16* ws_x  = ws;
    u16* ws_w1 = ws + W1OFF;
    u16* ws_w2 = ws + W2OFF;
    u16* ws_h1 = ws + H1OFF;
    float* h2  = (float*)(ws + H2OFF_U16);

    (void)hipMemsetAsync(ws_h1, 0, (size_t)H1TOT * 2, stream);
    prep<<<PREP_N / 256, 256, 0, stream>>>(x, w1_0, w1_1, w2_0, w2_1, ws);
    conv1_k<<<288, 256, 0, stream>>>(ws_x, ws_w1, ws_h1);
    conv2_k<<<288, 256, 0, stream>>>(ws_h1, ws_w2, h2);
    final_add<<<H2_PER / 4 / 256, 256, 0, stream>>>(x, h2, out);
}

// Round 13
// 138.037 us; speedup vs baseline: 1.1655x; 1.0953x over previous
//
#include <hip/hip_runtime.h>
#include <math.h>

// B=4, T=48, W=8, H=8, C=32; d_ff=64; periods {2,3,4}. T%P==0 always.
// (1x1 + 3^4)/2 inception folded into one 81-tap conv (center tap 40).
// R13 = R10 conv structure (best: issue-after-barrier 3-tap chunks, 4-wave
// blocks, 288 grid) + deduplicated storage: x as ONE unpadded 193-cell array
// (cell 192 = zeros), h1 as 3x193 cells. Convs select valid-cell-or-zero-cell
// per (dl,dq) group (wave-uniform). No 14MB memset; conv1 zeroes cell borders.

typedef __attribute__((ext_vector_type(8))) short bf16x8;
typedef __attribute__((ext_vector_type(4))) float f32x4;
typedef unsigned short u16;

// ---- workspace offsets (u16 units) ----
#define XC 3200                 // u16 per x cell (10*10*32)
#define HC 6400                 // u16 per h1 cell (10*10*64)
#define XSEG 617600             // 193 * XC   (cell 192 = zero cell)
#define ZSEG_END 636800         // + 3*6400 h1 zero cells
#define W1OFF 636800            // 165888 bf16: [tap 0..80][2048]
#define W2OFF 802688            // 165888 bf16: [tap 0..80][2048]
#define H1OFF 968576            // 3 periods x 193 cells x 6400
#define H1P 1235200             // per-period stride = 193*6400
#define H2OFF_U16 4674176       // H1OFF + 3*H1P (even)
#define H2_PER 393216           // fp32 per period: 192*64*32
#define PREP_N 1300352          // ZSEG_END + 2*165888 (weights follow zseg)

__device__ __forceinline__ u16 f2bf(float f) {
    unsigned u = __float_as_uint(f);
    unsigned r = u + 0x7fffu + ((u >> 16) & 1u);
    return (u16)(r >> 16);
}
__device__ __forceinline__ float gelu_exact(float v) {
    return 0.5f * v * (1.0f + erff(v * 0.7071067811865476f));
}

// async copy of 1 KB: 64 lanes x 16 B. LDS dest = wave-uniform base + lane*16.
__device__ __forceinline__ void cp1k(const u16* g, u16* l, int lane) {
    __builtin_amdgcn_global_load_lds(
        (const __attribute__((address_space(1))) unsigned int*)(g + lane * 8),
        (__attribute__((address_space(3))) unsigned int*)(l + lane * 8),
        16, 0, 0);
}

// ---- prep: x cells (swizzled) + h1 zero cells + effective bf16 weights ----
// x cell: addr = cellpos*32 + sc*8 + (c&7), sc = (c>>3)^(cellpos&3)
__global__ __launch_bounds__(256) void prep(
    const float* __restrict__ x,
    const float* __restrict__ w1_0, const float* __restrict__ w1_1,
    const float* __restrict__ w2_0, const float* __restrict__ w2_1,
    u16* __restrict__ ws) {
    int i = blockIdx.x * 256 + threadIdx.x;
    if (i < XSEG) {
        int cellidx = i / XC; int inner = i - cellidx * XC;
        int cellpos = inner >> 5; int low = inner & 31;
        int sc = low >> 3, jj = low & 7;
        int c = ((sc ^ (cellpos & 3)) << 3) + jj;
        int wp = cellpos / 10, hp = cellpos - (cellpos / 10) * 10;
        float v = 0.f;
        if (cellidx < 192 && wp >= 1 && wp <= 8 && hp >= 1 && hp <= 8)
            v = x[(cellidx * 64 + (wp - 1) * 8 + (hp - 1)) * 32 + c];
        ws[i] = f2bf(v);
    } else if (i < ZSEG_END) {
        int j = i - XSEG;                 // 3 h1 zero cells
        int per = j / HC; int off = j - per * HC;
        ws[H1OFF + per * H1P + 192 * HC + off] = 0;
    } else if (i < ZSEG_END + 165888) {
        // w1: [tap][chunk(256)*8+jj], chunk = (quad*4+nt4)*16+m
        int j = i - W1OFF;
        int tap = j >> 11; int r = j & 2047;
        int chunk = r >> 3, jj = r & 7;
        int m = chunk & 15, nt = (chunk >> 4) & 3, quad = chunk >> 6;
        int o = nt * 16 + m, c = quad * 8 + jj;
        float v = 0.5f * w1_1[(o * 32 + c) * 81 + tap];
        if (tap == 40) v += 0.5f * w1_0[o * 32 + c];
        ws[i] = f2bf(v);
    } else if (i < PREP_N) {
        // w2: [tap][chunk(256)*8+jj], chunk = ((ks*4+quad)*2+nt)*16+m
        int j = i - W2OFF;
        int tap = j >> 11; int r = j & 2047;
        int chunk = r >> 3, jj = r & 7;
        int m = chunk & 15, nt = (chunk >> 4) & 1;
        int quad = (chunk >> 5) & 3, ks = chunk >> 7;
        int o = nt * 16 + m, c = ks * 32 + quad * 8 + jj;
        float v = 0.5f * w2_1[(o * 64 + c) * 81 + tap];
        if (tap == 40) v += 0.5f * w2_0[o * 64 + c];
        ws[i] = f2bf(v);
    }
}

// cell index for (b, l2, q2): valid -> b*48 + l2*P + q2, else zero cell 192
template<int P>
__device__ __forceinline__ int cidx(int bb, int l2, int q2) {
    constexpr int L = 48 / P;
    return ((unsigned)l2 < (unsigned)L && (unsigned)q2 < (unsigned)P)
               ? bb * 48 + l2 * P + q2 : 192;
}

// ---- conv1 (C32->C64) + GELU. Block = 4 waves: (tloc, nh) = (wv>>1, wv&1).
// Wave: M=64 (its t), N=32 (its o-half). Weights shared block-wide. ----
template<int P>
__device__ __forceinline__ void conv1_body(
    const u16* __restrict__ xs, const u16* __restrict__ w1b,
    u16* __restrict__ h1, int tp, int bb,
    u16* __restrict__ s_w, u16* __restrict__ s_a) {
    constexpr int HB = (P == 2) ? 0 : (P == 3) ? H1P : 2 * H1P;

    int tid = threadIdx.x;
    int lane = tid & 63, wv = tid >> 6;
    int m = lane & 15, quad = lane >> 4;
    int tloc = wv >> 1, nh = wv & 1;

    int t0 = tp * 2, t1 = tp * 2 + 1;
    int l0 = t0 / P, q0 = t0 - l0 * P;
    int l1 = t1 / P, q1 = t1 - l1 * P;

    int sp[4];
#pragma unroll
    for (int mt = 0; mt < 4; ++mt) {
        int pos = mt * 16 + m;
        sp[mt] = (pos >> 3) * 10 + (pos & 7);
    }

    f32x4 acc[4][2];
#pragma unroll
    for (int mt = 0; mt < 4; ++mt)
#pragma unroll
        for (int nt = 0; nt < 2; ++nt) acc[mt][nt] = f32x4{0.f, 0.f, 0.f, 0.f};

    // weights chunk cgn = taps 3cgn..3cgn+2 (12 KB): 12 pieces, 3/wave
    auto stageW = [&](int cgn) {
        const u16* src = w1b + (cgn * 3) * 2048;
        u16* dst = s_w + (cgn & 1) * 6144;
        int p0 = wv * 3;
#pragma unroll
        for (int i = 0; i < 3; ++i)
            cp1k(src + (p0 + i) * 512, dst + (p0 + i) * 512, lane);
    };
    // act group gg: 2 cells x 7 pieces = 14, split across 3 chunks
    auto stageA = [&](int gg, int k0, int k1) {
        int dl = gg / 3, dq = gg - (gg / 3) * 3;
        const u16* c0 = xs + cidx<P>(bb, l0 + dl - 1, q0 + dq - 1) * XC;
        const u16* c1 = xs + cidx<P>(bb, l1 + dl - 1, q1 + dq - 1) * XC;
        for (int k = k0 + wv; k < k1; k += 4) {
            int cell = k / 7, pc = k - (k / 7) * 7;
            cp1k((cell ? c1 : c0) + pc * 512,
                 s_a + (cell * 2 + (gg & 1)) * 3584 + pc * 512, lane);
        }
    };

    stageW(0);
    stageA(0, 0, 14);

#pragma unroll 1
    for (int cg = 0; cg < 27; ++cg) {
        __syncthreads();   // implicit vmcnt(0): chunk cg delivered; all waves
                           // done with cg-1 -> safe to overwrite its buffers
        if (cg < 26) stageW(cg + 1);
        int grp = cg / 3, part = cg - grp * 3;
        if (grp < 8) stageA(grp + 1, part * 5, (part == 2) ? 14 : part * 5 + 5);

        const u16* bw = s_w + (cg & 1) * 6144;
        const u16* ba = s_a + (tloc * 2 + (grp & 1)) * 3584;
        int dwb = part * 10;   // dw = part, dh = j
#pragma unroll
        for (int j = 0; j < 3; ++j) {
            const u16* tw = bw + j * 2048;
            bf16x8 wf[2];
#pragma unroll
            for (int nt = 0; nt < 2; ++nt)
                wf[nt] = *(const bf16x8*)(tw +
                    (((quad * 4 + nh * 2 + nt) * 16 + m) << 3));
            bf16x8 af[4];
#pragma unroll
            for (int mt = 0; mt < 4; ++mt) {
                int cellpos = sp[mt] + dwb + j;
                af[mt] = *(const bf16x8*)(ba + cellpos * 32 +
                                          ((quad ^ (cellpos & 3)) << 3));
            }
#pragma unroll
            for (int mt = 0; mt < 4; ++mt)
#pragma unroll
                for (int nt = 0; nt < 2; ++nt)
                    acc[mt][nt] = __builtin_amdgcn_mfma_f32_16x16x32_bf16(
                        af[mt], wf[nt], acc[mt][nt], 0, 0, 0);
        }
    }

    // epilogue: GELU -> bf16 -> swizzled h1 cell interior + zero borders
    int t = tp * 2 + tloc;
    u16* hcell = h1 + HB + (bb * 48 + t) * HC;
#pragma unroll
    for (int mt = 0; mt < 4; ++mt)
#pragma unroll
        for (int r = 0; r < 4; ++r) {
            int pos = mt * 16 + quad * 4 + r;
            int cellpos = ((pos >> 3) + 1) * 10 + (pos & 7) + 1;
#pragma unroll
            for (int nt = 0; nt < 2; ++nt) {
                int o = nh * 32 + nt * 16 + m;
                hcell[cellpos * 64 + (((o >> 3) ^ (cellpos & 7)) << 3) + (o & 7)] =
                    f2bf(gelu_exact(acc[mt][nt][r]));
            }
        }
    // zero the 36 border cellpos (both nh waves duplicate: benign zero race)
    unsigned int* h32 = (unsigned int*)hcell;
#pragma unroll
    for (int it = 0; it < 18; ++it) {
        int k = it * 64 + lane;            // k in [0, 1152)
        int bp = k >> 5, u = k & 31;
        int cp;
        if (bp < 10) cp = bp;
        else if (bp < 20) cp = 90 + (bp - 10);
        else if (bp < 28) cp = (bp - 19) * 10;
        else cp = (bp - 27) * 10 + 9;
        h32[cp * 32 + u] = 0;
    }
}

__global__ __launch_bounds__(256) void conv1_k(
    const u16* __restrict__ ws_x, const u16* __restrict__ ws_w1,
    u16* __restrict__ ws_h1) {
    __shared__ __align__(16) u16 s_w[2 * 6144];   // 24 KB weight dbuf
    __shared__ __align__(16) u16 s_a[4 * 3584];   // 28 KB act [cell(2)][dbuf(2)]
    int g = blockIdx.x;
    int jid = (g & 7) * 36 + (g >> 3);            // XCD-chunked, 288 = 8*36
    int per = jid / 96; int rem = jid - per * 96;
    int bb = rem / 24; int tp = rem - bb * 24;
    if (per == 0)      conv1_body<2>(ws_x, ws_w1, ws_h1, tp, bb, s_w, s_a);
    else if (per == 1) conv1_body<3>(ws_x, ws_w1, ws_h1, tp, bb, s_w, s_a);
    else               conv1_body<4>(ws_x, ws_w1, ws_h1, tp, bb, s_w, s_a);
}

// ---- conv2 (C64->C32). Block = 4 waves: (tloc, mh) = (wv>>1, wv&1).
// Wave: M=32 (its pos-half), N=32 (all o), K=64. ----
template<int P>
__device__ __forceinline__ void conv2_body(
    const u16* __restrict__ h1, const u16* __restrict__ w2b,
    float* __restrict__ h2per, int tp, int bb,
    u16* __restrict__ s_w, u16* __restrict__ s_a) {
    constexpr int HB = (P == 2) ? 0 : (P == 3) ? H1P : 2 * H1P;

    int tid = threadIdx.x;
    int lane = tid & 63, wv = tid >> 6;
    int m = lane & 15, quad = lane >> 4;
    int tloc = wv >> 1, mh = wv & 1;

    int t0 = tp * 2, t1 = tp * 2 + 1;
    int l0 = t0 / P, q0 = t0 - l0 * P;
    int l1 = t1 / P, q1 = t1 - l1 * P;
    const u16* hb = h1 + HB;

    int sp[2];
#pragma unroll
    for (int mt = 0; mt < 2; ++mt) {
        int pos = mh * 32 + mt * 16 + m;
        sp[mt] = (pos >> 3) * 10 + (pos & 7);
    }

    f32x4 acc[2][2];
#pragma unroll
    for (int mt = 0; mt < 2; ++mt)
#pragma unroll
        for (int nt = 0; nt < 2; ++nt) acc[mt][nt] = f32x4{0.f, 0.f, 0.f, 0.f};

    auto stageW = [&](int cgn) {
        const u16* src = w2b + (cgn * 3) * 2048;
        u16* dst = s_w + (cgn & 1) * 6144;
        int p0 = wv * 3;
#pragma unroll
        for (int i = 0; i < 3; ++i)
            cp1k(src + (p0 + i) * 512, dst + (p0 + i) * 512, lane);
    };
    // act group gg: 2 cells x 13 pieces = 26, split across 3 chunks
    auto stageA = [&](int gg, int k0, int k1) {
        int dl = gg / 3, dq = gg - (gg / 3) * 3;
        const u16* c0 = hb + cidx<P>(bb, l0 + dl - 1, q0 + dq - 1) * HC;
        const u16* c1 = hb + cidx<P>(bb, l1 + dl - 1, q1 + dq - 1) * HC;
        for (int k = k0 + wv; k < k1; k += 4) {
            int cell = k / 13, pc = k - (k / 13) * 13;
            cp1k((cell ? c1 : c0) + pc * 512,
                 s_a + (cell * 2 + (gg & 1)) * 6656 + pc * 512, lane);
        }
    };

    stageW(0);
    stageA(0, 0, 26);

#pragma unroll 1
    for (int cg = 0; cg < 27; ++cg) {
        __syncthreads();
        if (cg < 26) stageW(cg + 1);
        int grp = cg / 3, part = cg - grp * 3;
        if (grp < 8) stageA(grp + 1, part * 9, (part == 2) ? 26 : part * 9 + 9);

        const u16* bw = s_w + (cg & 1) * 6144;
        const u16* ba = s_a + (tloc * 2 + (grp & 1)) * 6656;
        int dwb = part * 10;
#pragma unroll
        for (int j = 0; j < 3; ++j) {
            const u16* tw = bw + j * 2048;
            bf16x8 wf[2][2];   // [nt][ks]
#pragma unroll
            for (int nt = 0; nt < 2; ++nt)
#pragma unroll
                for (int ks = 0; ks < 2; ++ks)
                    wf[nt][ks] = *(const bf16x8*)(tw +
                        ((((ks * 4 + quad) * 2 + nt) * 16 + m) << 3));
            bf16x8 af[2][2];   // [mt][ks]
#pragma unroll
            for (int mt = 0; mt < 2; ++mt) {
                int cellpos = sp[mt] + dwb + j;
#pragma unroll
                for (int ks = 0; ks < 2; ++ks)
                    af[mt][ks] = *(const bf16x8*)(ba + cellpos * 64 +
                        (((ks * 4 + quad) ^ (cellpos & 7)) << 3));
            }
#pragma unroll
            for (int mt = 0; mt < 2; ++mt)
#pragma unroll
                for (int ks = 0; ks < 2; ++ks)
#pragma unroll
                    for (int nt = 0; nt < 2; ++nt)
                        acc[mt][nt] = __builtin_amdgcn_mfma_f32_16x16x32_bf16(
                            af[mt][ks], wf[nt][ks], acc[mt][nt], 0, 0, 0);
        }
    }

    int t = tp * 2 + tloc;
    float* orow = h2per + (bb * 48 + t) * 2048;
#pragma unroll
    for (int mt = 0; mt < 2; ++mt)
#pragma unroll
        for (int nt = 0; nt < 2; ++nt)
#pragma unroll
            for (int r = 0; r < 4; ++r) {
                int pos = mh * 32 + mt * 16 + quad * 4 + r;
                orow[pos * 32 + nt * 16 + m] = acc[mt][nt][r];
            }
}

__global__ __launch_bounds__(256) void conv2_k(
    const u16* __restrict__ ws_h1, const u16* __restrict__ ws_w2,
    float* __restrict__ h2) {
    __shared__ __align__(16) u16 s_w[2 * 6144];   // 24 KB
    __shared__ __align__(16) u16 s_a[4 * 6656];   // 52 KB -> 76 KB total
    int g = blockIdx.x;
    int jid = (g & 7) * 36 + (g >> 3);            // same XCD mapping as conv1
    int per = jid / 96; int rem = jid - per * 96;
    int bb = rem / 24; int tp = rem - bb * 24;
    float* h2per = h2 + per * H2_PER;
    if (per == 0)      conv2_body<2>(ws_h1, ws_w2, h2per, tp, bb, s_w, s_a);
    else if (per == 1) conv2_body<3>(ws_h1, ws_w2, h2per, tp, bb, s_w, s_a);
    else               conv2_body<4>(ws_h1, ws_w2, h2per, tp, bb, s_w, s_a);
}

// ---- out = x + (h2_p0 + h2_p1 + h2_p2) / 3 ----
__global__ __launch_bounds__(256) void final_add(
    const float* __restrict__ x, const float* __restrict__ h2,
    float* __restrict__ out) {
    int i = blockIdx.x * 256 + threadIdx.x;
    float4 xv = ((const float4*)x)[i];
    float4 a = ((const float4*)h2)[i];
    float4 bv = ((const float4*)(h2 + H2_PER))[i];
    float4 cv = ((const float4*)(h2 + 2 * H2_PER))[i];
    const float s = 1.0f / 3.0f;
    float4 o;
    o.x = xv.x + (a.x + bv.x + cv.x) * s;
    o.y = xv.y + (a.y + bv.y + cv.y) * s;
    o.z = xv.z + (a.z + bv.z + cv.z) * s;
    o.w = xv.w + (a.w + bv.w + cv.w) * s;
    ((float4*)out)[i] = o;
}

extern "C" void kernel_launch(void* const* d_in, const int* in_sizes, int n_in,
                              void* d_out, int out_size, void* d_ws, size_t ws_size,
                              hipStream_t stream) {
    const float* x    = (const float*)d_in[0];
    const float* w1_0 = (const float*)d_in[1];
    const float* w1_1 = (const float*)d_in[2];
    const float* w2_0 = (const float*)d_in[3];
    const float* w2_1 = (const float*)d_in[4];
    float* out = (float*)d_out;

    u16* ws = (u16*)d_ws;
    u16* ws_x  = ws;                 // 193 cells (192 real + zero)
    u16* ws_w1 = ws + W1OFF;
    u16* ws_w2 = ws + W2OFF;
    u16* ws_h1 = ws + H1OFF;         // 3 x 193 cells
    float* h2  = (float*)(ws + H2OFF_U16);

    prep<<<(PREP_N + 255) / 256, 256, 0, stream>>>(
        x, w1_0, w1_1, w2_0, w2_1, ws);
    conv1_k<<<288, 256, 0, stream>>>(ws_x, ws_w1, ws_h1);
    conv2_k<<<288, 256, 0, stream>>>(ws_h1, ws_w2, h2);
    final_add<<<H2_PER / 4 / 256, 256, 0, stream>>>(x, h2, out);
}

// Round 14
// 129.066 us; speedup vs baseline: 1.2465x; 1.0695x over previous
//
#include <hip/hip_runtime.h>
#include <math.h>

// B=4, T=48, W=8, H=8, C=32; d_ff=64; periods {2,3,4}. T%P==0 always.
// (1x1 + 3^4)/2 inception folded into one 81-tap conv (center tap 40).
// R14 = R13 + (a) conv1 depth-2 pipeline: 4-deep weight ring, issue cg+2,
// wait-own-queue vmcnt(N) BEFORE raw s_barrier (barrier publishes delivery),
// (b) final_add eliminated: prep writes out=x, conv2 atomicAdds acc/3.

typedef __attribute__((ext_vector_type(8))) short bf16x8;
typedef __attribute__((ext_vector_type(4))) float f32x4;
typedef unsigned short u16;

// ---- workspace offsets (u16 units) ----
#define XC 3200                 // u16 per x cell (10*10*32)
#define HC 6400                 // u16 per h1 cell (10*10*64)
#define XSEG 617600             // 193 * XC   (cell 192 = zero cell)
#define ZSEG_END 636800         // + 3*6400 h1 zero cells
#define W1OFF 636800            // 165888 bf16: [tap 0..80][2048]
#define W2OFF 802688            // 165888 bf16: [tap 0..80][2048]
#define H1OFF 968576            // 3 periods x 193 cells x 6400
#define H1P 1235200             // per-period stride = 193*6400
#define PREP_N 1300352          // end of weight segment
#define OUT_Q 98304             // out-init float4 count (393216 fp32)
#define PREP_TOT (PREP_N + OUT_Q)

#define WAITVM(N) asm volatile("s_waitcnt vmcnt(" #N ")" ::: "memory")
#define SBAR()    asm volatile("s_barrier" ::: "memory")

__device__ __forceinline__ u16 f2bf(float f) {
    unsigned u = __float_as_uint(f);
    unsigned r = u + 0x7fffu + ((u >> 16) & 1u);
    return (u16)(r >> 16);
}
__device__ __forceinline__ float gelu_exact(float v) {
    return 0.5f * v * (1.0f + erff(v * 0.7071067811865476f));
}

// async copy of 1 KB: 64 lanes x 16 B. LDS dest = wave-uniform base + lane*16.
__device__ __forceinline__ void cp1k(const u16* g, u16* l, int lane) {
    __builtin_amdgcn_global_load_lds(
        (const __attribute__((address_space(1))) unsigned int*)(g + lane * 8),
        (__attribute__((address_space(3))) unsigned int*)(l + lane * 8),
        16, 0, 0);
}

// ---- prep: x cells (swizzled) + h1 zero cells + weights + out = x ----
__global__ __launch_bounds__(256) void prep(
    const float* __restrict__ x,
    const float* __restrict__ w1_0, const float* __restrict__ w1_1,
    const float* __restrict__ w2_0, const float* __restrict__ w2_1,
    u16* __restrict__ ws, float* __restrict__ out) {
    int i = blockIdx.x * 256 + threadIdx.x;
    if (i < XSEG) {
        int cellidx = i / XC; int inner = i - cellidx * XC;
        int cellpos = inner >> 5; int low = inner & 31;
        int sc = low >> 3, jj = low & 7;
        int c = ((sc ^ (cellpos & 3)) << 3) + jj;
        int wp = cellpos / 10, hp = cellpos - (cellpos / 10) * 10;
        float v = 0.f;
        if (cellidx < 192 && wp >= 1 && wp <= 8 && hp >= 1 && hp <= 8)
            v = x[(cellidx * 64 + (wp - 1) * 8 + (hp - 1)) * 32 + c];
        ws[i] = f2bf(v);
    } else if (i < ZSEG_END) {
        int j = i - XSEG;                 // 3 h1 zero cells
        int per = j / HC; int off = j - per * HC;
        ws[H1OFF + per * H1P + 192 * HC + off] = 0;
    } else if (i < ZSEG_END + 165888) {
        // w1: [tap][chunk(256)*8+jj], chunk = (quad*4+nt4)*16+m
        int j = i - W1OFF;
        int tap = j >> 11; int r = j & 2047;
        int chunk = r >> 3, jj = r & 7;
        int m = chunk & 15, nt = (chunk >> 4) & 3, quad = chunk >> 6;
        int o = nt * 16 + m, c = quad * 8 + jj;
        float v = 0.5f * w1_1[(o * 32 + c) * 81 + tap];
        if (tap == 40) v += 0.5f * w1_0[o * 32 + c];
        ws[i] = f2bf(v);
    } else if (i < PREP_N) {
        // w2: [tap][chunk(256)*8+jj], chunk = ((ks*4+quad)*2+nt)*16+m
        int j = i - W2OFF;
        int tap = j >> 11; int r = j & 2047;
        int chunk = r >> 3, jj = r & 7;
        int m = chunk & 15, nt = (chunk >> 4) & 1;
        int quad = (chunk >> 5) & 3, ks = chunk >> 7;
        int o = nt * 16 + m, c = ks * 32 + quad * 8 + jj;
        float v = 0.5f * w2_1[(o * 64 + c) * 81 + tap];
        if (tap == 40) v += 0.5f * w2_0[o * 64 + c];
        ws[i] = f2bf(v);
    } else if (i < PREP_TOT) {
        int j = i - PREP_N;
        ((float4*)out)[j] = ((const float4*)x)[j];
    }
}

// cell index for (b, l2, q2): valid -> b*48 + l2*P + q2, else zero cell 192
template<int P>
__device__ __forceinline__ int cidx(int bb, int l2, int q2) {
    constexpr int L = 48 / P;
    return ((unsigned)l2 < (unsigned)L && (unsigned)q2 < (unsigned)P)
               ? bb * 48 + l2 * P + q2 : 192;
}

// ---- conv1 (C32->C64) + GELU. Block = 4 waves: (tloc, nh) = (wv>>1, wv&1).
// Depth-2 pipeline: 4-deep weight ring, wait-before-barrier. ----
template<int P>
__device__ __forceinline__ void conv1_body(
    const u16* __restrict__ xs, const u16* __restrict__ w1b,
    u16* __restrict__ h1, int tp, int bb,
    u16* __restrict__ s_w, u16* __restrict__ s_a) {
    constexpr int HB = (P == 2) ? 0 : (P == 3) ? H1P : 2 * H1P;

    int tid = threadIdx.x;
    int lane = tid & 63, wv = tid >> 6;
    int m = lane & 15, quad = lane >> 4;
    int tloc = wv >> 1, nh = wv & 1;

    int t0 = tp * 2, t1 = tp * 2 + 1;
    int l0 = t0 / P, q0 = t0 - l0 * P;
    int l1 = t1 / P, q1 = t1 - l1 * P;

    int sp[4];
#pragma unroll
    for (int mt = 0; mt < 4; ++mt) {
        int pos = mt * 16 + m;
        sp[mt] = (pos >> 3) * 10 + (pos & 7);
    }

    f32x4 acc[4][2];
#pragma unroll
    for (int mt = 0; mt < 4; ++mt)
#pragma unroll
        for (int nt = 0; nt < 2; ++nt) acc[mt][nt] = f32x4{0.f, 0.f, 0.f, 0.f};

    // weights chunk cgn = taps 3cgn..3cgn+2 (12 pieces): 3/wave, slot cgn&3
    auto stageW = [&](int cgn) {
        const u16* src = w1b + (cgn * 3) * 2048;
        u16* dst = s_w + (cgn & 3) * 6144;
        int p0 = wv * 3;
#pragma unroll
        for (int i = 0; i < 3; ++i)
            cp1k(src + (p0 + i) * 512, dst + (p0 + i) * 512, lane);
    };
    // act group gg: 2 cells x 7 pieces = 14 padded to 16 -> 4/wave (uniform;
    // k>=14 duplicates piece 13: same src+dst, benign)
    auto stageA = [&](int gg) {
        int dl = gg / 3, dq = gg - (gg / 3) * 3;
        const u16* c0 = xs + cidx<P>(bb, l0 + dl - 1, q0 + dq - 1) * XC;
        const u16* c1 = xs + cidx<P>(bb, l1 + dl - 1, q1 + dq - 1) * XC;
#pragma unroll
        for (int i = 0; i < 4; ++i) {
            int k = wv * 4 + i; if (k >= 14) k = 13;
            int cell = k / 7, pc = k - (k / 7) * 7;
            cp1k((cell ? c1 : c0) + pc * 512,
                 s_a + (cell * 2 + (gg & 1)) * 3584 + pc * 512, lane);
        }
    };

    // prologue: chunks 0 (W+A0) and 1 (W). per-wave outstanding = 3+4+3 = 10
    stageW(0); stageA(0); stageW(1);

#pragma unroll 1
    for (int cg = 0; cg < 27; ++cg) {
        // issue chunk cg+2 (slot (cg+2)&3: distinct from readers of cg-1,
        // cg, and in-flight cg+1 under mod-4). A(g) rides with chunk 3g.
        if (cg < 25) {
            stageW(cg + 2);
            if ((cg + 2) % 3 == 0) stageA((cg + 2) / 3);
        }
        // wait own queue: chunk cg delivered; leave cg+1, cg+2 in flight.
        // P(chunk c) = 3 + (4 if c%3==0). Traced: cg%3==0 -> 6, else 10;
        // tail: cg=25 -> 3, cg=26 -> 0.
        if (cg == 25) { WAITVM(3); }
        else if (cg == 26) { WAITVM(0); }
        else if (cg % 3 == 0) { WAITVM(6); }
        else { WAITVM(10); }
        SBAR();   // publishes: every wave's chunk-cg pieces delivered; and
                  // all waves finished compute cg-1 before next overwrite.

        int grp = cg / 3, part = cg - grp * 3;
        const u16* bw = s_w + (cg & 3) * 6144;
        const u16* ba = s_a + (tloc * 2 + (grp & 1)) * 3584;
        int dwb = part * 10;   // dw = part, dh = j
#pragma unroll
        for (int j = 0; j < 3; ++j) {
            const u16* tw = bw + j * 2048;
            bf16x8 wf[2];
#pragma unroll
            for (int nt = 0; nt < 2; ++nt)
                wf[nt] = *(const bf16x8*)(tw +
                    (((quad * 4 + nh * 2 + nt) * 16 + m) << 3));
            bf16x8 af[4];
#pragma unroll
            for (int mt = 0; mt < 4; ++mt) {
                int cellpos = sp[mt] + dwb + j;
                af[mt] = *(const bf16x8*)(ba + cellpos * 32 +
                                          ((quad ^ (cellpos & 3)) << 3));
            }
#pragma unroll
            for (int mt = 0; mt < 4; ++mt)
#pragma unroll
                for (int nt = 0; nt < 2; ++nt)
                    acc[mt][nt] = __builtin_amdgcn_mfma_f32_16x16x32_bf16(
                        af[mt], wf[nt], acc[mt][nt], 0, 0, 0);
        }
    }

    // epilogue: GELU -> bf16 -> swizzled h1 cell interior + zero borders
    int t = tp * 2 + tloc;
    u16* hcell = h1 + HB + (bb * 48 + t) * HC;
#pragma unroll
    for (int mt = 0; mt < 4; ++mt)
#pragma unroll
        for (int r = 0; r < 4; ++r) {
            int pos = mt * 16 + quad * 4 + r;
            int cellpos = ((pos >> 3) + 1) * 10 + (pos & 7) + 1;
#pragma unroll
            for (int nt = 0; nt < 2; ++nt) {
                int o = nh * 32 + nt * 16 + m;
                hcell[cellpos * 64 + (((o >> 3) ^ (cellpos & 7)) << 3) + (o & 7)] =
                    f2bf(gelu_exact(acc[mt][nt][r]));
            }
        }
    // zero the 36 border cellpos (both nh waves duplicate: benign zero race)
    unsigned int* h32 = (unsigned int*)hcell;
#pragma unroll
    for (int it = 0; it < 18; ++it) {
        int k = it * 64 + lane;
        int bp = k >> 5, u = k & 31;
        int cp;
        if (bp < 10) cp = bp;
        else if (bp < 20) cp = 90 + (bp - 10);
        else if (bp < 28) cp = (bp - 19) * 10;
        else cp = (bp - 27) * 10 + 9;
        h32[cp * 32 + u] = 0;
    }
}

__global__ __launch_bounds__(256) void conv1_k(
    const u16* __restrict__ ws_x, const u16* __restrict__ ws_w1,
    u16* __restrict__ ws_h1) {
    __shared__ __align__(16) u16 s_w[4 * 6144];   // 48 KB weight ring (4-deep)
    __shared__ __align__(16) u16 s_a[4 * 3584];   // 28 KB -> 76 KB, 2 blk/CU
    int g = blockIdx.x;
    int jid = (g & 7) * 36 + (g >> 3);            // XCD-chunked, 288 = 8*36
    int per = jid / 96; int rem = jid - per * 96;
    int bb = rem / 24; int tp = rem - bb * 24;
    if (per == 0)      conv1_body<2>(ws_x, ws_w1, ws_h1, tp, bb, s_w, s_a);
    else if (per == 1) conv1_body<3>(ws_x, ws_w1, ws_h1, tp, bb, s_w, s_a);
    else               conv1_body<4>(ws_x, ws_w1, ws_h1, tp, bb, s_w, s_a);
}

// ---- conv2 (C64->C32). Block = 4 waves: (tloc, mh) = (wv>>1, wv&1).
// R13 depth-1 pipeline; epilogue: atomicAdd acc/3 into out. ----
template<int P>
__device__ __forceinline__ void conv2_body(
    const u16* __restrict__ h1, const u16* __restrict__ w2b,
    float* __restrict__ out, int tp, int bb,
    u16* __restrict__ s_w, u16* __restrict__ s_a) {
    constexpr int HB = (P == 2) ? 0 : (P == 3) ? H1P : 2 * H1P;

    int tid = threadIdx.x;
    int lane = tid & 63, wv = tid >> 6;
    int m = lane & 15, quad = lane >> 4;
    int tloc = wv >> 1, mh = wv & 1;

    int t0 = tp * 2, t1 = tp * 2 + 1;
    int l0 = t0 / P, q0 = t0 - l0 * P;
    int l1 = t1 / P, q1 = t1 - l1 * P;
    const u16* hb = h1 + HB;

    int sp[2];
#pragma unroll
    for (int mt = 0; mt < 2; ++mt) {
        int pos = mh * 32 + mt * 16 + m;
        sp[mt] = (pos >> 3) * 10 + (pos & 7);
    }

    f32x4 acc[2][2];
#pragma unroll
    for (int mt = 0; mt < 2; ++mt)
#pragma unroll
        for (int nt = 0; nt < 2; ++nt) acc[mt][nt] = f32x4{0.f, 0.f, 0.f, 0.f};

    auto stageW = [&](int cgn) {
        const u16* src = w2b + (cgn * 3) * 2048;
        u16* dst = s_w + (cgn & 1) * 6144;
        int p0 = wv * 3;
#pragma unroll
        for (int i = 0; i < 3; ++i)
            cp1k(src + (p0 + i) * 512, dst + (p0 + i) * 512, lane);
    };
    auto stageA = [&](int gg, int k0, int k1) {
        int dl = gg / 3, dq = gg - (gg / 3) * 3;
        const u16* c0 = hb + cidx<P>(bb, l0 + dl - 1, q0 + dq - 1) * HC;
        const u16* c1 = hb + cidx<P>(bb, l1 + dl - 1, q1 + dq - 1) * HC;
        for (int k = k0 + wv; k < k1; k += 4) {
            int cell = k / 13, pc = k - (k / 13) * 13;
            cp1k((cell ? c1 : c0) + pc * 512,
                 s_a + (cell * 2 + (gg & 1)) * 6656 + pc * 512, lane);
        }
    };

    stageW(0);
    stageA(0, 0, 26);

#pragma unroll 1
    for (int cg = 0; cg < 27; ++cg) {
        __syncthreads();
        if (cg < 26) stageW(cg + 1);
        int grp = cg / 3, part = cg - grp * 3;
        if (grp < 8) stageA(grp + 1, part * 9, (part == 2) ? 26 : part * 9 + 9);

        const u16* bw = s_w + (cg & 1) * 6144;
        const u16* ba = s_a + (tloc * 2 + (grp & 1)) * 6656;
        int dwb = part * 10;
#pragma unroll
        for (int j = 0; j < 3; ++j) {
            const u16* tw = bw + j * 2048;
            bf16x8 wf[2][2];   // [nt][ks]
#pragma unroll
            for (int nt = 0; nt < 2; ++nt)
#pragma unroll
                for (int ks = 0; ks < 2; ++ks)
                    wf[nt][ks] = *(const bf16x8*)(tw +
                        ((((ks * 4 + quad) * 2 + nt) * 16 + m) << 3));
            bf16x8 af[2][2];   // [mt][ks]
#pragma unroll
            for (int mt = 0; mt < 2; ++mt) {
                int cellpos = sp[mt] + dwb + j;
#pragma unroll
                for (int ks = 0; ks < 2; ++ks)
                    af[mt][ks] = *(const bf16x8*)(ba + cellpos * 64 +
                        (((ks * 4 + quad) ^ (cellpos & 7)) << 3));
            }
#pragma unroll
            for (int mt = 0; mt < 2; ++mt)
#pragma unroll
                for (int ks = 0; ks < 2; ++ks)
#pragma unroll
                    for (int nt = 0; nt < 2; ++nt)
                        acc[mt][nt] = __builtin_amdgcn_mfma_f32_16x16x32_bf16(
                            af[mt][ks], wf[nt][ks], acc[mt][nt], 0, 0, 0);
        }
    }

    // epilogue: out += acc/3 (softmax(ones) weights); out pre-filled with x
    int t = tp * 2 + tloc;
    float* orow = out + (bb * 48 + t) * 2048;
    const float s = 1.0f / 3.0f;
#pragma unroll
    for (int mt = 0; mt < 2; ++mt)
#pragma unroll
        for (int nt = 0; nt < 2; ++nt)
#pragma unroll
            for (int r = 0; r < 4; ++r) {
                int pos = mh * 32 + mt * 16 + quad * 4 + r;
                atomicAdd(&orow[pos * 32 + nt * 16 + m], acc[mt][nt][r] * s);
            }
}

__global__ __launch_bounds__(256) void conv2_k(
    const u16* __restrict__ ws_h1, const u16* __restrict__ ws_w2,
    float* __restrict__ out) {
    __shared__ __align__(16) u16 s_w[2 * 6144];   // 24 KB
    __shared__ __align__(16) u16 s_a[4 * 6656];   // 52 KB -> 76 KB total
    int g = blockIdx.x;
    int jid = (g & 7) * 36 + (g >> 3);            // same XCD mapping as conv1
    int per = jid / 96; int rem = jid - per * 96;
    int bb = rem / 24; int tp = rem - bb * 24;
    if (per == 0)      conv2_body<2>(ws_h1, ws_w2, out, tp, bb, s_w, s_a);
    else if (per == 1) conv2_body<3>(ws_h1, ws_w2, out, tp, bb, s_w, s_a);
    else               conv2_body<4>(ws_h1, ws_w2, out, tp, bb, s_w, s_a);
}

extern "C" void kernel_launch(void* const* d_in, const int* in_sizes, int n_in,
                              void* d_out, int out_size, void* d_ws, size_t ws_size,
                              hipStream_t stream) {
    const float* x    = (const float*)d_in[0];
    const float* w1_0 = (const float*)d_in[1];
    const float* w1_1 = (const float*)d_in[2];
    const float* w2_0 = (const float*)d_in[3];
    const float* w2_1 = (const float*)d_in[4];
    float* out = (float*)d_out;

    u16* ws = (u16*)d_ws;
    u16* ws_x  = ws;                 // 193 cells (192 real + zero)
    u16* ws_w1 = ws + W1OFF;
    u16* ws_w2 = ws + W2OFF;
    u16* ws_h1 = ws + H1OFF;         // 3 x 193 cells

    prep<<<(PREP_TOT + 255) / 256, 256, 0, stream>>>(
        x, w1_0, w1_1, w2_0, w2_1, ws, out);
    conv1_k<<<288, 256, 0, stream>>>(ws_x, ws_w1, ws_h1);
    conv2_k<<<288, 256, 0, stream>>>(ws_h1, ws_w2, out);
}